// Round 11
// baseline (484.962 us; speedup 1.0000x reference)
//
#include <hip/hip_runtime.h>
#include <hip/hip_fp16.h>

#define BF 256
#define TSTEPS 256

typedef _Float16 h8_t __attribute__((ext_vector_type(8)));
typedef _Float16 h4_t __attribute__((ext_vector_type(4)));
typedef float f4_t __attribute__((ext_vector_type(4)));

union H8 { uint4 u; h8_t v; };
union H4 { uint2 u; h4_t v; };
union U2H4 { uint2 u; __half h[4]; };

// fast sigmoid/tanh: v_exp + v_rcp (error << f16 storage quantization of h)
static __device__ __forceinline__ float sigmoidf_(float x) {
    return __builtin_amdgcn_rcpf(1.f + __expf(-x));
}
static __device__ __forceinline__ float tanhf_(float x) {
    return 1.f - 2.f * __builtin_amdgcn_rcpf(__expf(2.f * x) + 1.f);
}

// xor-32 lane exchange on the VALU (v_permlane32_swap_b32) instead of the LDS
// crossbar (ds_swizzle). Bit-exact vs __shfl_xor(x,32).
static __device__ __forceinline__ float xswap32(float x, int lane) {
    typedef unsigned uv2 __attribute__((ext_vector_type(2)));
    unsigned xu = __float_as_uint(x);
    uv2 r = __builtin_amdgcn_permlane32_swap(xu, xu, false, false);
    return __uint_as_float((lane & 32) ? r[0] : r[1]);
}

// LDS-only workgroup barrier: drains lgkmcnt (ds ops) but leaves vmcnt
// (global stores of h / X prefetch loads) in flight across the barrier.
static __device__ __forceinline__ void wg_barrier_lds() {
    __builtin_amdgcn_sched_barrier(0);
    asm volatile("s_waitcnt lgkmcnt(0)" ::: "memory");
    __builtin_amdgcn_s_barrier();
    __builtin_amdgcn_sched_barrier(0);
}

// ---- pack helper: f16 MFMA operand layout -----------------------------------------
static __device__ __forceinline__ void pack_one(const float* __restrict__ src,
                                                __half* __restrict__ dst,
                                                int OC, int IC, int KS,
                                                int oc_str, int ic_str, int k_str, int i) {
    int grp = KS / 4;
    int j = i % grp;
    int oc = (i / grp) % OC;
    int g = (i / (grp * OC)) & 3;
    int chunk = i / (grp * OC * 4);
    int CPK = IC / KS;
    int cc = chunk % CPK;
    int khw = chunk / CPK;
    int ic = cc * KS + g * grp + j;
    dst[i] = __float2half(src[(long)oc * oc_str + (long)ic * ic_str + khw * k_str]);
}

// Whh/Wih pack with class-interleaved row permutation: packed row prow = T*16+cls*4+du
// maps to original row cls*128 + T*4 + du. A 16-row MFMA tile then holds
// 4 classes x 4 units; wave w (2 tiles) covers units [8w,8w+8) x all 4 classes.
static __device__ __forceinline__ void pack_whh_one(const float* __restrict__ src,
                                                    __half* __restrict__ dst, int i) {
    int j = i & 7;
    int prow = (i >> 3) & 511;
    int cg = i >> 12;            // chunk*4 + g
    int g = cg & 3, chunk = cg >> 2;
    int t = prow >> 4, rr = prow & 15;
    int cls = rr >> 2, du = rr & 3;
    int orig = cls * 128 + t * 4 + du;
    int ic = chunk * 32 + g * 8 + j;
    dst[i] = __float2half(src[orig * 128 + ic]);
}

// ---- fused weight prep ------------------------------------------------------------
// NOTE: Wih is packed class-interleaved (pack_whh_one) since it is consumed as
// the A-operand inside the fused lstm kernel, with the same tile map as Whh.
__global__ __launch_bounds__(256) void prep_k(
        const float* __restrict__ w0, const float* __restrict__ w1,
        const float* __restrict__ w2, const float* __restrict__ w3,
        const float* __restrict__ Wihf, const float* __restrict__ Wihb,
        const float* __restrict__ Whhf, const float* __restrict__ Whhb,
        float* __restrict__ w0t, __half* __restrict__ w1p,
        __half* __restrict__ w2p, __half* __restrict__ w3p,
        __half* __restrict__ wfp, __half* __restrict__ wbp,
        __half* __restrict__ whhfp, __half* __restrict__ whhbp) {
    int i = blockIdx.x * 256 + threadIdx.x;
    if (i < 144) { int oc = i / 9, rem = i % 9; w0t[rem * 16 + oc] = w0[i]; return; }
    i -= 144;
    if (i < 4608) { pack_one(w1, w1p, 32, 16, 16, 144, 9, 1, i); return; }
    i -= 4608;
    if (i < 18432) { pack_one(w2, w2p, 64, 32, 32, 288, 9, 1, i); return; }
    i -= 18432;
    if (i < 73728) { pack_one(w3, w3p, 128, 64, 32, 576, 9, 1, i); return; }
    i -= 73728;
    if (i < 65536) { pack_whh_one(Wihf, wfp, i); return; }
    i -= 65536;
    if (i < 65536) { pack_whh_one(Wihb, wbp, i); return; }
    i -= 65536;
    if (i < 65536) { pack_whh_one(Whhf, whhfp, i); return; }
    i -= 65536;
    if (i < 65536) { pack_whh_one(Whhb, whhbp, i); return; }
}

__global__ void pack_wf16(const float* __restrict__ src, __half* __restrict__ dst,
                          int OC, int IC, int KS,
                          int oc_str, int ic_str, int k_str, int total) {
    int i = blockIdx.x * 256 + threadIdx.x;
    if (i >= total) return;
    pack_one(src, dst, OC, IC, KS, oc_str, ic_str, k_str, i);
}

// ---- conv0: 1->16 ch, VALU, NHWC f16 out (uint4-packed stores) --------------------
__global__ __launch_bounds__(256) void conv0_k(const float* __restrict__ in,
                                               const float* __restrict__ wT,
                                               const float* __restrict__ bias,
                                               __half* __restrict__ out) {
    __shared__ float wsm[9][16];
    __shared__ float bs[16];
    int tid = threadIdx.x;
    if (tid < 144) wsm[tid / 16][tid % 16] = wT[tid];
    if (tid < 16) bs[tid] = bias[tid];
    __syncthreads();
    int gid = blockIdx.x * 256 + tid;
    int ow = gid % 27;
    int t = (gid / 27) % 256;
    int bf = gid / (27 * 256);
    float acc[16];
#pragma unroll
    for (int o = 0; o < 16; o++) acc[o] = bs[o];
    int iw0 = ow * 3 - 1;
#pragma unroll
    for (int kh = 0; kh < 3; kh++) {
        int tt = t + kh - 1;
        if ((unsigned)tt >= 256u) continue;
        const float* ip = in + ((long)bf * 256 + tt) * 81;
#pragma unroll
        for (int kw = 0; kw < 3; kw++) {
            int iw = iw0 + kw;
            if ((unsigned)iw >= 81u) continue;
            float x = ip[iw];
#pragma unroll
            for (int o = 0; o < 16; o++) acc[o] += x * wsm[kh * 3 + kw][o];
        }
    }
    union OU { uint4 u; __half2 h2[4]; } o0, o1;
#pragma unroll
    for (int o = 0; o < 4; o++)
        o0.h2[o] = __floats2half2_rn(fmaxf(acc[2 * o], 0.f), fmaxf(acc[2 * o + 1], 0.f));
#pragma unroll
    for (int o = 0; o < 4; o++)
        o1.h2[o] = __floats2half2_rn(fmaxf(acc[8 + 2 * o], 0.f), fmaxf(acc[9 + 2 * o], 0.f));
    uint4* op = (uint4*)(out + (long)gid * 16);
    op[0] = o0.u;
    op[1] = o1.u;
}

// ---- MFMA implicit-GEMM conv: NHWC f16 in/out -------------------------------------
template<int IC, int OC, int WIN, int WOUT, int KS>
__global__ __launch_bounds__(256) void convM_k(const __half* __restrict__ in,
                                               const __half* __restrict__ wp,
                                               const float* __restrict__ bias,
                                               __half* __restrict__ out) {
    constexpr int NT = OC / 16;
    constexpr int CPK = IC / KS;
    constexpr int NCHUNK = 9 * CPK;
    constexpr int GRP = KS / 4;
    int tid = threadIdx.x;
    int lane = tid & 63;
    int wv = tid >> 6;
    int l15 = lane & 15;
    int g = lane >> 4;
    int m = blockIdx.x * 64 + wv * 16 + l15;
    int ow = m % WOUT;
    int t = (m / WOUT) % 256;
    int bf = m / (WOUT * 256);

    f4_t acc[NT];
#pragma unroll
    for (int nt = 0; nt < NT; nt++)
#pragma unroll
        for (int r = 0; r < 4; r++) acc[nt][r] = 0.f;

#pragma unroll
    for (int chunk = 0; chunk < NCHUNK; chunk++) {
        int khw = chunk / CPK, cc = chunk % CPK;
        int kh = khw / 3;
        int kw = khw - kh * 3;
        int tt = t + kh - 1;
        int iw = ow * 3 + kw - 1;
        bool ok = ((unsigned)tt < 256u) && ((unsigned)iw < (unsigned)WIN);
        long aoff = ok ? (((long)(bf * 256 + tt) * WIN + iw) * IC + cc * KS + g * GRP) : 0;
        if constexpr (KS == 32) {
            H8 af;
            af.u = *(const uint4*)(in + aoff);
            if (!ok) af.u = make_uint4(0u, 0u, 0u, 0u);
#pragma unroll
            for (int nt = 0; nt < NT; nt++) {
                H8 bf8;
                bf8.u = *(const uint4*)(wp + ((long)(chunk * 4 + g) * OC + nt * 16 + l15) * GRP);
                acc[nt] = __builtin_amdgcn_mfma_f32_16x16x32_f16(af.v, bf8.v, acc[nt], 0, 0, 0);
            }
        } else {
            H4 af;
            af.u = *(const uint2*)(in + aoff);
            if (!ok) af.u = make_uint2(0u, 0u);
#pragma unroll
            for (int nt = 0; nt < NT; nt++) {
                H4 bf4;
                bf4.u = *(const uint2*)(wp + ((long)(chunk * 4 + g) * OC + nt * 16 + l15) * GRP);
                acc[nt] = __builtin_amdgcn_mfma_f32_16x16x16f16(af.v, bf4.v, acc[nt], 0, 0, 0);
            }
        }
    }
    int orow = blockIdx.x * 64 + wv * 16 + g * 4;
#pragma unroll
    for (int nt = 0; nt < NT; nt++) {
        int oc = nt * 16 + l15;
        float b = bias[oc];
#pragma unroll
        for (int r = 0; r < 4; r++) {
            float v = fmaxf(acc[nt][r] + b, 0.f);
            out[(long)(orow + r) * OC + oc] = __float2half(v);
        }
    }
}

// ---- FUSED LSTM: gates (Wih@x) computed in-kernel, SPREAD window pipeline ---------
// R10 did the window producer (8 MFMA chain + zsc store/read + X prefetch) as one
// serial bunch at the window boundary -> ~800cy/window exposed, all 16 waves at
// once. Now the producer for window to+1 is SPREAD across window to's 8 steps:
//   ti=0..3 : one z-MFMA chunk per step (2 MFMA, chain latency hidden by steps)
//   ti=4    : issue X prefetch for window to+2 (bxr regs free after ti=3)
//   ti=5    : store z -> zsc (drained for free by this step's lgkm barrier)
//   ti=6    : read gcn (next window's gate row) from zsc
// Boundary becomes a register move (gc = gcn). Chunk order identical -> bit-exact.
__global__ __launch_bounds__(1024, 4) void lstm_k(const __half* __restrict__ X,
                                                  const __half* __restrict__ wihfp,
                                                  const __half* __restrict__ wihbp,
                                                  const __half* __restrict__ whhfp,
                                                  const __half* __restrict__ whhbp,
                                                  const float* __restrict__ bihf,
                                                  const float* __restrict__ bhhf,
                                                  const float* __restrict__ bihb,
                                                  const float* __restrict__ bhhb,
                                                  __half* __restrict__ flat) {
    int bid = blockIdx.x;
    int dir = bid >> 7;
    int b0 = (bid & 127) * 2;
    const __half* wp  = dir ? whhbp : whhfp;
    const __half* wip = dir ? wihbp : wihfp;
    const float* bA = dir ? bihb : bihf;
    const float* bB = dir ? bhhb : bhhf;
    int tid = threadIdx.x;
    int w = tid >> 6;            // wave 0..15
    int lane = tid & 63;
    int l15 = lane & 15;
    int g2 = lane >> 4;          // class: 0=i, 1=f, 2=g, 3=o
    int chn = l15 >> 3;          // seq within block
    int u8 = l15 & 7;            // unit within wave's 8
    int unit = w * 8 + u8;       // 0..127
    int tsel = (u8 >> 2) & 1;
    int du = u8 & 3;
    int tw = l15 & 7;            // producer col timestep-within-window

    // A-frags: Whh + Wih, each 2 tiles x 4 k-chunks
    H8 afr[2][4], aih[2][4];
#pragma unroll
    for (int t = 0; t < 2; t++) {
        int prow = (w * 2 + t) * 16 + l15;
#pragma unroll
        for (int c = 0; c < 4; c++) {
            afr[t][c].u = *(const uint4*)(wp  + ((long)((c * 4 + g2) * 512 + prow)) * 8);
            aih[t][c].u = *(const uint4*)(wip + ((long)((c * 4 + g2) * 512 + prow)) * 8);
        }
    }
    float cbias = bA[g2 * 128 + unit] + bB[g2 * 128 + unit];

    __shared__ __align__(16) __half hbuf[2][2][128];
    __shared__ __align__(16) __half zsc[16][32][36];   // per-wave z_ih scratch, padded
    if (tid < 256) hbuf[0][tid >> 7][tid & 127] = __float2half(0.f);
    __syncthreads();

    const f4_t zero4 = {0.f, 0.f, 0.f, 0.f};
    float cst = 0.f;                         // cell state, valid on g2==1 lanes
    float ma = (g2 == 2) ? 2.f : 1.f;        // tanh(z) = 2*sigmoid(2z)-1 on g-lanes
    float mb = ma;
    float cb = (g2 == 2) ? -1.f : 0.f;
    long fbase = (long)(b0 + chn) * 65536 + dir * 128 + unit;
    long xrow = (long)(b0 + chn) * 256;

    H8 gc, gcn;                              // current / next window gate rows
    H8 bxr0, bxr1, bxr2, bxr3;               // prefetched X (one window ahead)
    f4_t zw0, zw1;                           // in-flight z accumulators

    // issue X loads for window wnd (latency hides under ~4 steps of work)
    auto issueX = [&](int wnd) {
        int tp = dir ? (255 - (wnd * 8 + tw)) : (wnd * 8 + tw);
        const __half* xb = X + (xrow + tp) * 128 + g2 * 8;
        bxr0.u = *(const uint4*)(xb);
        bxr1.u = *(const uint4*)(xb + 32);
        bxr2.u = *(const uint4*)(xb + 64);
        bxr3.u = *(const uint4*)(xb + 96);
    };
    auto storeZ = [&]() {
#pragma unroll
        for (int r = 0; r < 4; r++) {
            zsc[w][g2 * 4 + r][l15]      = __float2half(zw0[r]);
            zsc[w][16 + g2 * 4 + r][l15] = __float2half(zw1[r]);
        }
    };

    // prologue: window 0 computed serially (latency exposed once)
    issueX(0);
    zw0 = __builtin_amdgcn_mfma_f32_16x16x32_f16(aih[0][0].v, bxr0.v, zero4, 0, 0, 0);
    zw1 = __builtin_amdgcn_mfma_f32_16x16x32_f16(aih[1][0].v, bxr0.v, zero4, 0, 0, 0);
    zw0 = __builtin_amdgcn_mfma_f32_16x16x32_f16(aih[0][1].v, bxr1.v, zw0, 0, 0, 0);
    zw1 = __builtin_amdgcn_mfma_f32_16x16x32_f16(aih[1][1].v, bxr1.v, zw1, 0, 0, 0);
    zw0 = __builtin_amdgcn_mfma_f32_16x16x32_f16(aih[0][2].v, bxr2.v, zw0, 0, 0, 0);
    zw1 = __builtin_amdgcn_mfma_f32_16x16x32_f16(aih[1][2].v, bxr2.v, zw1, 0, 0, 0);
    zw0 = __builtin_amdgcn_mfma_f32_16x16x32_f16(aih[0][3].v, bxr3.v, zw0, 0, 0, 0);
    zw1 = __builtin_amdgcn_mfma_f32_16x16x32_f16(aih[1][3].v, bxr3.v, zw1, 0, 0, 0);
    storeZ();
    // LDS ops are in-order per wave: this read sees the stores above.
    gc.u = *(const uint4*)&zsc[w][tsel * 16 + g2 * 4 + du][chn * 8];
    issueX(1);                               // bxr for window 1, in flight

    for (int to = 0; to < 32; to++) {
        bool prod = (to < 31);
#pragma unroll
        for (int ti = 0; ti < 8; ti++) {
            int s = to * 8 + ti;
            int p = s & 1;
            H8 bfr[4];
#pragma unroll
            for (int c = 0; c < 4; c++)
                bfr[c].u = *(const uint4*)(&hbuf[p][chn][c * 32 + g2 * 8]);

            f4_t acc[2];
#pragma unroll
            for (int t = 0; t < 2; t++)
                acc[t] = __builtin_amdgcn_mfma_f32_16x16x32_f16(afr[t][0].v, bfr[0].v,
                                                                zero4, 0, 0, 0);
#pragma unroll
            for (int c = 1; c < 4; c++)
#pragma unroll
                for (int t = 0; t < 2; t++)
                    acc[t] = __builtin_amdgcn_mfma_f32_16x16x32_f16(afr[t][c].v, bfr[c].v,
                                                                    acc[t], 0, 0, 0);

            // ---- spread producer for window to+1 (ti is compile-time) ----
            if (prod) {
                if (ti == 0) {
                    zw0 = __builtin_amdgcn_mfma_f32_16x16x32_f16(aih[0][0].v, bxr0.v, zero4, 0, 0, 0);
                    zw1 = __builtin_amdgcn_mfma_f32_16x16x32_f16(aih[1][0].v, bxr0.v, zero4, 0, 0, 0);
                } else if (ti == 1) {
                    zw0 = __builtin_amdgcn_mfma_f32_16x16x32_f16(aih[0][1].v, bxr1.v, zw0, 0, 0, 0);
                    zw1 = __builtin_amdgcn_mfma_f32_16x16x32_f16(aih[1][1].v, bxr1.v, zw1, 0, 0, 0);
                } else if (ti == 2) {
                    zw0 = __builtin_amdgcn_mfma_f32_16x16x32_f16(aih[0][2].v, bxr2.v, zw0, 0, 0, 0);
                    zw1 = __builtin_amdgcn_mfma_f32_16x16x32_f16(aih[1][2].v, bxr2.v, zw1, 0, 0, 0);
                } else if (ti == 3) {
                    zw0 = __builtin_amdgcn_mfma_f32_16x16x32_f16(aih[0][3].v, bxr3.v, zw0, 0, 0, 0);
                    zw1 = __builtin_amdgcn_mfma_f32_16x16x32_f16(aih[1][3].v, bxr3.v, zw1, 0, 0, 0);
                } else if (ti == 4) {
                    if (to < 30) issueX(to + 2);
                } else if (ti == 5) {
                    storeZ();               // drained by this step's lgkm barrier
                } else if (ti == 6) {
                    gcn.u = *(const uint4*)&zsc[w][tsel * 16 + g2 * 4 + du][chn * 8];
                }
            }

            // select acc[tsel][du]
            f4_t at;
#pragma unroll
            for (int e = 0; e < 4; e++) at[e] = tsel ? acc[1][e] : acc[0][e];
            float lo = (du & 1) ? at[1] : at[0];
            float hi = (du & 1) ? at[3] : at[2];
            float ev = (du & 2) ? hi : lo;

            float z = ev + (float)gc.v[ti] + cbias;
            float a = sigmoidf_(ma * z) * mb + cb;   // i,f,o: sigmoid; g: tanh

            float x1 = xswap32(a, lane);             // i<->g, f<->o (VALU permlane)
            float pi = a * x1;                       // on g2=0: sig(i)*tanh(g)
            float x2 = __shfl_xor(pi, 16, 64);       // g2=1 <- g2=0
            float cn = a * cst + x2;                 // on g2=1: sig(f)*c + pi
            cst = cn;
            float tc = tanhf_(cn);
            float x3 = xswap32(tc, lane);            // g2=3 <- g2=1 (VALU permlane)
            float h = a * x3;                        // on g2=3: sig(o)*tanh(c')

            if (g2 == 3) {
                __half hh = __float2half(h);
                int ts = dir ? (255 - s) : s;
                hbuf[p ^ 1][chn][unit] = hh;
                flat[fbase + (long)ts * 256] = hh;
            }
            wg_barrier_lds();
        }
        gc = gcn;                            // boundary = register move
    }
}

// ---- FC1 MFMA split-K: z[256][128] += flat16 @ fc1_w16^T --------------------------
__global__ __launch_bounds__(256) void fc1m_k(const __half* __restrict__ flat,
                                              const __half* __restrict__ wp,
                                              float* __restrict__ z) {
    int tid = threadIdx.x;
    int lane = tid & 63;
    int wv = tid >> 6;
    int l15 = lane & 15;
    int g = lane >> 4;
    int m0 = blockIdx.x * 64 + wv * 16;
    long k0 = (long)blockIdx.y * 1024;

    f4_t acc[8];
#pragma unroll
    for (int nt = 0; nt < 8; nt++)
#pragma unroll
        for (int r = 0; r < 4; r++) acc[nt][r] = 0.f;

    for (int c = 0; c < 32; c++) {
        long chunk = (k0 >> 5) + c;
        H8 af;
        af.u = *(const uint4*)(flat + (long)(m0 + l15) * 65536 + k0 + c * 32 + g * 8);
#pragma unroll
        for (int nt = 0; nt < 8; nt++) {
            H8 bw;
            bw.u = *(const uint4*)(wp + ((chunk * 4 + g) * 128 + nt * 16 + l15) * 8);
            acc[nt] = __builtin_amdgcn_mfma_f32_16x16x32_f16(af.v, bw.v, acc[nt], 0, 0, 0);
        }
    }
#pragma unroll
    for (int nt = 0; nt < 8; nt++)
#pragma unroll
        for (int r = 0; r < 4; r++)
            atomicAdd(&z[(m0 + g * 4 + r) * 128 + nt * 16 + l15], acc[nt][r]);
}

__global__ void zero_k(float* __restrict__ p, int n) {
    int i = blockIdx.x * 256 + threadIdx.x;
    if (i < n) p[i] = 0.f;
}

// ---- head -------------------------------------------------------------------------
__global__ __launch_bounds__(256) void head_k(const float* __restrict__ z,
                                              const float* __restrict__ b1,
                                              const float* __restrict__ fsw,
                                              const float* __restrict__ fsb,
                                              float* __restrict__ out) {
    __shared__ float sf[256];
    int r = threadIdx.x;
    float acc = fsb[0];
#pragma unroll
    for (int j4 = 0; j4 < 32; j4++) {
        float4 zv = *(const float4*)&z[r * 128 + j4 * 4];
        float4 bv = *(const float4*)&b1[j4 * 4];
        float4 wv = *(const float4*)&fsw[j4 * 4];
        acc += fmaxf(zv.x + bv.x, 0.f) * wv.x;
        acc += fmaxf(zv.y + bv.y, 0.f) * wv.y;
        acc += fmaxf(zv.z + bv.z, 0.f) * wv.z;
        acc += fmaxf(zv.w + bv.w, 0.f) * wv.w;
    }
    float val = sigmoidf_(acc) * 4.f + 1.f;
    out[16 + r] = val;
    sf[r] = val;
    __syncthreads();
    if (r < 16) {
        float m = 0.f;
#pragma unroll
        for (int f = 0; f < 16; f++) m += sf[r * 16 + f];
        out[r] = m * (1.f / 16.f);
    }
}

extern "C" void kernel_launch(void* const* d_in, const int* in_sizes, int n_in,
                              void* d_out, int out_size, void* d_ws, size_t ws_size,
                              hipStream_t stream) {
    const float* audio = (const float*)d_in[0];
    const float* w0 = (const float*)d_in[2];
    const float* b0 = (const float*)d_in[3];
    const float* w1 = (const float*)d_in[4];
    const float* b1 = (const float*)d_in[5];
    const float* w2 = (const float*)d_in[6];
    const float* b2 = (const float*)d_in[7];
    const float* w3 = (const float*)d_in[8];
    const float* b3 = (const float*)d_in[9];
    const float* Wih_f = (const float*)d_in[10];
    const float* Whh_f = (const float*)d_in[11];
    const float* bih_f = (const float*)d_in[12];
    const float* bhh_f = (const float*)d_in[13];
    const float* Wih_b = (const float*)d_in[14];
    const float* Whh_b = (const float*)d_in[15];
    const float* bih_b = (const float*)d_in[16];
    const float* bhh_b = (const float*)d_in[17];
    const float* fc1_w = (const float*)d_in[18];
    const float* fc1_b = (const float*)d_in[19];
    const float* fs_w = (const float*)d_in[20];
    const float* fs_b = (const float*)d_in[21];
    float* out = (float*)d_out;

    char* ws = (char*)d_ws;
    // lifetimes: out1 dies before fc1p; out0 dies before flat16
    __half* out1  = (__half*)(ws);                    // 37.7 MB
    __half* fc1p  = (__half*)(ws);                    // 16.8 MB (post-lstm)
    __half* flat16= (__half*)(ws + 134217728);        // 33.6 MB
    __half* out0  = (__half*)(ws + 134217728);        // 56.6 MB (pre-flat16)
    __half* X     = (__half*)(ws + 201326592);        // 16.8 MB
    __half* out2  = (__half*)(ws + 218103808);        // 25.2 MB
    char* rd = ws + 243269632;
    float*  w0t   = (float*)(rd);
    __half* w1p   = (__half*)(rd + 1024);
    __half* w2p   = (__half*)(rd + 10240);
    __half* w3p   = (__half*)(rd + 47104);
    __half* wfp   = (__half*)(rd + 194560);
    __half* wbp   = (__half*)(rd + 325632);
    __half* whhfp = (__half*)(rd + 456704);
    __half* whhbp = (__half*)(rd + 587776);
    float*  zbuf  = (float*)(rd + 718848);

    // fused weight prep (1 launch)
    prep_k<<<1403, 256, 0, stream>>>(w0, w1, w2, w3, Wih_f, Wih_b, Whh_f, Whh_b,
                                     w0t, w1p, w2p, w3p, wfp, wbp, whhfp, whhbp);

    // conv chain (NHWC f16)
    conv0_k<<<6912, 256, 0, stream>>>(audio, w0t, b0, out0);
    convM_k<16, 32, 27, 9, 16><<<9216, 256, 0, stream>>>(out0, w1p, b1, out1);
    convM_k<32, 64, 9, 3, 32><<<3072, 256, 0, stream>>>(out1, w2p, b2, out2);
    convM_k<64, 128, 3, 1, 32><<<1024, 256, 0, stream>>>(out2, w3p, b3, X);

    // fused recurrence: gates in-kernel, producer pipelined across steps
    lstm_k<<<256, 1024, 0, stream>>>(X, wfp, wbp, whhfp, whhbp,
                                     bih_f, bhh_f, bih_b, bhh_b, flat16);

    // FC head: pack fc1_w (into dead out1 region), split-K MFMA, head
    pack_wf16<<<32768, 256, 0, stream>>>(fc1_w, fc1p, 128, 65536, 32, 65536, 1, 0, 8388608);
    zero_k<<<128, 256, 0, stream>>>(zbuf, 256 * 128);
    fc1m_k<<<dim3(4, 64), 256, 0, stream>>>(flat16, fc1p, zbuf);
    head_k<<<1, 256, 0, stream>>>(zbuf, fc1_b, fs_w, fs_b, out);
}